// Round 5
// baseline (181.339 us; speedup 1.0000x reference)
//
#include <hip/hip_runtime.h>
#include <hip/hip_bf16.h>
#include <cstddef>
#include <cstdint>

#define D_MODEL   256
#define N_HEADS   8
#define N_LEVELS  4
#define N_POINTS  4
#define D_HEAD    32
#define HLP       128      // N_HEADS*N_LEVELS*N_POINTS
#define NBATCH    4
#define LQ        4096
#define S_LEN     7680     // 4096+2048+1024+512
#define QB        8        // queries per sample block

typedef __attribute__((ext_vector_type(8))) short  short8;
typedef __attribute__((ext_vector_type(4))) float  f32x4;
typedef __attribute__((ext_vector_type(8))) unsigned short ushort8;

__device__ __forceinline__ unsigned short f2bf(float x) {
    __hip_bfloat16 h = __float2bfloat16(x);
    return *reinterpret_cast<unsigned short*>(&h);
}
__device__ __forceinline__ float bf2f(unsigned short u) {
    unsigned int v = ((unsigned int)u) << 16;
    return *reinterpret_cast<float*>(&v);
}

__device__ __forceinline__ void gload_lds16(const void* g, void* l) {
    __builtin_amdgcn_global_load_lds(
        (const __attribute__((address_space(1))) void*)g,
        (__attribute__((address_space(3))) void*)l,
        16, 0, 0);
}

// ---------------------------------------------------------------------------
// Fused weight prep: transpose [K=256][N] fp32 -> [N][K=256] bf16 for
// W_v (z=0), [W_off|W_aw] concat (z=1), W_out (z=2). Block (0,0,1) also
// writes bcat = [b_off|b_aw]. Grid (4,4,3), 256 threads.
// ---------------------------------------------------------------------------
__global__ __launch_bounds__(256) void prep_kernel(
    const float* __restrict__ W_v,  const float* __restrict__ W_off,
    const float* __restrict__ W_aw, const float* __restrict__ W_out,
    const float* __restrict__ b_off, const float* __restrict__ b_aw,
    unsigned short* __restrict__ Wv_t, unsigned short* __restrict__ Wcat_t,
    unsigned short* __restrict__ Wout_t, float* __restrict__ bcat)
{
    __shared__ float t[64][65];
    const int z   = blockIdx.z;
    const int k0  = blockIdx.y * 64;
    const int n0  = blockIdx.x * 64;
    const int tid = threadIdx.x;

    const float* src; int srcN; int cs; unsigned short* dst;
    if (z == 0)      { src = W_v;   srcN = 256; cs = n0;       dst = Wv_t;  }
    else if (z == 2) { src = W_out; srcN = 256; cs = n0;       dst = Wout_t;}
    else if (n0 < 128){ src = W_off; srcN = 128; cs = n0;      dst = Wcat_t;}
    else             { src = W_aw;  srcN = 128; cs = n0 - 128; dst = Wcat_t;}

    #pragma unroll
    for (int i = 0; i < 16; ++i) {
        int idx = tid + i * 256;
        int kk = idx >> 6, nn = idx & 63;
        t[kk][nn] = src[(size_t)(k0 + kk) * srcN + cs + nn];
    }
    __syncthreads();
    #pragma unroll
    for (int i = 0; i < 16; ++i) {
        int idx = tid + i * 256;
        int nn = idx >> 6, kk = idx & 63;
        dst[(size_t)(n0 + nn) * 256 + k0 + kk] = f2bf(t[kk][nn]);
    }
    if (z == 1 && blockIdx.x == 0 && blockIdx.y == 0) {
        bcat[tid] = (tid < 128) ? b_off[tid] : b_aw[tid - 128];
    }
}

// ---------------------------------------------------------------------------
// Fused value-GEMM + P-GEMM. Grid 736 blocks, 256 thr (4 waves, 2x2).
// job < 480 : value tile -> value3 bf16, layout [n][m][s][32]
// job >= 480: P tile     -> P fp32 [nq][256]
// A fp32 row-major (converted while staging); Bt bf16 N-major [n][k].
// 128x128 tile, 16x16x32 MFMA, BK=32.
// ---------------------------------------------------------------------------
__global__ __launch_bounds__(256) void gemm_vp_kernel(
    const float* __restrict__ inflat, const float* __restrict__ query,
    const unsigned short* __restrict__ Wv_t, const unsigned short* __restrict__ Wcat_t,
    const float* __restrict__ b_v, const float* __restrict__ bcat,
    unsigned short* __restrict__ value3, float* __restrict__ P)
{
    __shared__ alignas(16) unsigned short Als[8][64][8];
    __shared__ alignas(16) unsigned short Bls[8][64][8];

    const int job = blockIdx.x;
    const bool is_val = (job < 480);
    const int jj   = is_val ? job : (job - 480);
    const int row0 = (jj >> 1) * 128;
    const int col0 = (jj & 1) * 128;
    const float* A = is_val ? inflat : query;
    const unsigned short* Bt = is_val ? Wv_t : Wcat_t;
    const float* bias = is_val ? b_v : bcat;

    const int tid  = threadIdx.x;
    const int lane = tid & 63;
    const int w    = tid >> 6;
    const int wm   = w & 1;
    const int wn   = w >> 1;
    const int lr   = lane & 15;
    const int lk   = (lane >> 4) * 8;

    f32x4 acc[4][4] = {};

    for (int kt = 0; kt < 8; ++kt) {
        const int k0 = kt * 32;
        #pragma unroll
        for (int c = 0; c < 2; ++c) {
            const int im = w * 2 + c;
            const float* ap = A + (size_t)(row0 + im * 16 + lr) * 256 + k0 + lk;
            const float4 a0 = *(const float4*)(ap);
            const float4 a1 = *(const float4*)(ap + 4);
            short8 pk;
            pk[0] = (short)f2bf(a0.x); pk[1] = (short)f2bf(a0.y);
            pk[2] = (short)f2bf(a0.z); pk[3] = (short)f2bf(a0.w);
            pk[4] = (short)f2bf(a1.x); pk[5] = (short)f2bf(a1.y);
            pk[6] = (short)f2bf(a1.z); pk[7] = (short)f2bf(a1.w);
            *(short8*)&Als[im][lane][0] = pk;
            const size_t gb = (size_t)(col0 + im * 16 + lr) * 256 + k0 + lk;
            gload_lds16(Bt + gb, &Bls[im][0][0]);
        }
        __syncthreads();

        short8 af[4], bfr[4];
        #pragma unroll
        for (int i = 0; i < 4; ++i) af[i]  = *(const short8*)&Als[wm * 4 + i][lane][0];
        #pragma unroll
        for (int j = 0; j < 4; ++j) bfr[j] = *(const short8*)&Bls[wn * 4 + j][lane][0];

        #pragma unroll
        for (int i = 0; i < 4; ++i)
            #pragma unroll
            for (int j = 0; j < 4; ++j)
                acc[i][j] = __builtin_amdgcn_mfma_f32_16x16x32_bf16(
                    af[i], bfr[j], acc[i][j], 0, 0, 0);
        __syncthreads();
    }

    const int prow = (lane >> 4) * 4;
    const int pcol = lane & 15;
    if (is_val) {
        // row = n*7680 + s (7680 = 60*128: blocks never straddle n)
        const int n  = row0 / S_LEN;
        const int s0 = row0 - n * S_LEN;
        #pragma unroll
        for (int j = 0; j < 4; ++j) {
            const int col = col0 + wn * 64 + j * 16 + pcol;   // 0..255
            const float bs = bias[col];
            const int m = col >> 5, d = col & 31;
            unsigned short* dst = value3 + ((size_t)(n * 8 + m) * S_LEN + s0) * 32 + d;
            #pragma unroll
            for (int i = 0; i < 4; ++i) {
                #pragma unroll
                for (int r = 0; r < 4; ++r) {
                    const int rl = wm * 64 + i * 16 + prow + r;
                    dst[(size_t)rl * 32] = f2bf(acc[i][j][r] + bs);
                }
            }
        }
    } else {
        #pragma unroll
        for (int j = 0; j < 4; ++j) {
            const int col = col0 + wn * 64 + j * 16 + pcol;
            const float bs = bias[col];
            #pragma unroll
            for (int i = 0; i < 4; ++i) {
                #pragma unroll
                for (int r = 0; r < 4; ++r) {
                    const int row = row0 + wm * 64 + i * 16 + prow + r;
                    P[(size_t)row * 256 + col] = acc[i][j][r] + bs;
                }
            }
        }
    }
}

// ---------------------------------------------------------------------------
// Fused sampling + softmax + out-projection. 2048 blocks, 256 threads.
// blockIdx&7 -> (n, q-half): batch n's 3.93 MB value slice stays in the
// two XCDs serving it. Each block: QB=8 queries.
//   phase 1: locations/logits -> LDS tables
//   phase 2: per-(q,head) softmax
//   phase 3: gather from value3[n][m][s][32] (i0,i1 rows are ADJACENT 64 B)
//            -> T[q][256] bf16 in LDS
//   phase 4: out[8x256] = T @ W_out + b_out via MFMA (M padded to 16)
// ---------------------------------------------------------------------------
__global__ __launch_bounds__(256) void sample_out_kernel(
    const float* __restrict__ P, const float* __restrict__ refp,
    const int* __restrict__ shapes, const int* __restrict__ lstart,
    const unsigned short* __restrict__ value3,
    const unsigned short* __restrict__ Wout_t,
    const float* __restrict__ b_out,
    float* __restrict__ out)
{
    __shared__ int   sG0[QB][132];
    __shared__ float sW [QB][132];
    __shared__ float sA [QB][132];
    __shared__ alignas(16) unsigned short T[16][264];
    __shared__ int glim[4];

    const int b    = blockIdx.x;       // 0..2047
    const int xcd  = b & 7;
    const int n    = xcd >> 1;
    const int half = xcd & 1;
    const int slot = b >> 3;           // 0..255
    const int q0   = (slot * 2 + half) * QB;
    const int nq0  = n * LQ + q0;
    const int tid  = threadIdx.x;

    if (tid < 4) glim[tid] = lstart[tid] + shapes[tid] - 1;

    // ---- phase 1: 8 queries x 128 points ----
    #pragma unroll
    for (int it = 0; it < 4; ++it) {
        const int idx = tid + it * 256;   // 0..1023
        const int q   = idx >> 7;
        const int j   = idx & 127;        // m*16 + l*4 + p
        const int l   = (j >> 2) & 3;
        const int nq  = nq0 + q;
        const float off   = __builtin_nontemporal_load(P + (size_t)nq * 256 + j);
        const float logit = __builtin_nontemporal_load(P + (size_t)nq * 256 + 128 + j);
        const float ref   = __builtin_nontemporal_load(refp + (size_t)nq * N_LEVELS + l);
        const int   sh    = shapes[l];
        const float Tf    = (float)sh;
        float x = ref * Tf + off - 0.5f;
        x = fminf(fmaxf(x, 0.0f), Tf - 1.0f);
        const float x0 = floorf(x);
        sG0[q][j] = (int)x0 + lstart[l];
        sW [q][j] = x - x0;
        sA [q][j] = logit;
    }
    __syncthreads();

    // ---- phase 2: softmax per (q, head); also zero T rows 8..15 ----
    if (tid < 64) {
        const int q = tid >> 3;
        const int m = tid & 7;
        float e[16];
        float mx = -1e30f;
        #pragma unroll
        for (int i = 0; i < 16; ++i) { e[i] = sA[q][m * 16 + i]; mx = fmaxf(mx, e[i]); }
        float s = 0.f;
        #pragma unroll
        for (int i = 0; i < 16; ++i) { e[i] = __expf(e[i] - mx); s += e[i]; }
        const float rs = 1.0f / s;
        #pragma unroll
        for (int i = 0; i < 16; ++i) sA[q][m * 16 + i] = e[i] * rs;
    }
    {   // zero pad rows 8..15 (cols 0..255): 256 thr x 16 B
        const int zr = 8 + (tid >> 5);
        const int zc = (tid & 31) * 8;
        *(ushort8*)&T[zr][zc] = (ushort8)0;
    }
    __syncthreads();

    // ---- phase 3: gather + interpolate -> T ----
    {
        const int q  = tid >> 5;          // 0..7
        const int r  = tid & 31;
        const int m  = r >> 2;            // head
        const int ql = r & 3;             // 8-dim group
        const unsigned short* vb =
            value3 + (size_t)(n * 8 + m) * S_LEN * 32 + ql * 8;

        float acc[8] = {};
        #pragma unroll
        for (int i = 0; i < 16; ++i) {
            const int j = m * 16 + i;
            const float a  = sA[q][j];
            const float ww = sW[q][j];
            const int g0 = sG0[q][j];
            const int g1 = min(g0 + 1, glim[i >> 2]);
            const ushort8 u0 = *(const ushort8*)(vb + (size_t)g0 * 32);
            const ushort8 u1 = *(const ushort8*)(vb + (size_t)g1 * 32);
            #pragma unroll
            for (int d = 0; d < 8; ++d) {
                const float v0 = bf2f(u0[d]);
                const float v1 = bf2f(u1[d]);
                acc[d] += a * (v0 + ww * (v1 - v0));
            }
        }
        ushort8 o;
        #pragma unroll
        for (int d = 0; d < 8; ++d) o[d] = f2bf(acc[d]);
        *(ushort8*)&T[q][m * 32 + ql * 8] = o;
    }
    __syncthreads();

    // ---- phase 4: out-proj, wave w covers cols w*64..w*64+63 ----
    {
        const int w    = tid >> 6;
        const int lane = tid & 63;
        const int lr   = lane & 15;
        const int lk   = (lane >> 4) * 8;
        f32x4 acc4[4] = {};
        for (int kt = 0; kt < 8; ++kt) {
            const short8 af = *(const short8*)&T[lr][kt * 32 + lk];
            #pragma unroll
            for (int j = 0; j < 4; ++j) {
                const int col = w * 64 + j * 16 + lr;
                const short8 bf = *(const short8*)(Wout_t + (size_t)col * 256 + kt * 32 + lk);
                acc4[j] = __builtin_amdgcn_mfma_f32_16x16x32_bf16(af, bf, acc4[j], 0, 0, 0);
            }
        }
        const int prow = (lane >> 4) * 4;   // rows prow..prow+3 valid if < 8
        if (prow < 8) {
            #pragma unroll
            for (int j = 0; j < 4; ++j) {
                const int col = w * 64 + j * 16 + lr;
                const float bs = b_out[col];
                #pragma unroll
                for (int r = 0; r < 4; ++r) {
                    const int row = prow + r;
                    out[(size_t)(nq0 + row) * 256 + col] = acc4[j][r] + bs;
                }
            }
        }
    }
}

// ---------------------------------------------------------------------------
extern "C" void kernel_launch(void* const* d_in, const int* in_sizes, int n_in,
                              void* d_out, int out_size, void* d_ws, size_t ws_size,
                              hipStream_t stream)
{
    const float* query  = (const float*)d_in[0];
    const float* refp   = (const float*)d_in[1];
    const float* inflat = (const float*)d_in[2];
    const int*   shapes = (const int*)d_in[3];
    const int*   lstart = (const int*)d_in[4];
    const float* W_off  = (const float*)d_in[5];
    const float* b_off  = (const float*)d_in[6];
    const float* W_aw   = (const float*)d_in[7];
    const float* b_aw   = (const float*)d_in[8];
    const float* W_v    = (const float*)d_in[9];
    const float* b_v    = (const float*)d_in[10];
    const float* W_out  = (const float*)d_in[11];
    const float* b_out  = (const float*)d_in[12];

    const int M_val = NBATCH * S_LEN;    // 30720
    const int M_q   = NBATCH * LQ;       // 16384

    // ---- workspace layout ----
    char* p = (char*)d_ws;
    unsigned short* value3 = (unsigned short*)p; p += (size_t)M_val * D_MODEL * 2; // 15.7 MB
    float*          P      = (float*)p;          p += (size_t)M_q * 256 * 4;       // 16.8 MB
    unsigned short* Wv_t   = (unsigned short*)p; p += 256 * 256 * 2;
    unsigned short* Wcat_t = (unsigned short*)p; p += 256 * 256 * 2;
    unsigned short* Wout_t = (unsigned short*)p; p += 256 * 256 * 2;
    float*          bcat   = (float*)p;          p += 256 * 4;

    // 1. weight prep
    prep_kernel<<<dim3(4, 4, 3), 256, 0, stream>>>(
        W_v, W_off, W_aw, W_out, b_off, b_aw, Wv_t, Wcat_t, Wout_t, bcat);
    // 2. value-GEMM (480 jobs) + P-GEMM (256 jobs), one dispatch
    gemm_vp_kernel<<<736, 256, 0, stream>>>(
        inflat, query, Wv_t, Wcat_t, b_v, bcat, value3, P);
    // 3. fused sampling + softmax + out-proj
    sample_out_kernel<<<2048, 256, 0, stream>>>(
        P, refp, shapes, lstart, value3, Wout_t, b_out, (float*)d_out);
}

// Round 6
// 161.746 us; speedup vs baseline: 1.1211x; 1.1211x over previous
//
#include <hip/hip_runtime.h>
#include <hip/hip_bf16.h>
#include <cstddef>
#include <cstdint>

#define D_MODEL   256
#define N_HEADS   8
#define N_LEVELS  4
#define N_POINTS  4
#define D_HEAD    32
#define HLP       128      // N_HEADS*N_LEVELS*N_POINTS
#define NBATCH    4
#define LQ        4096
#define S_LEN     7680     // 4096+2048+1024+512
#define QB        8        // queries per sample block

typedef __attribute__((ext_vector_type(8))) short  short8;
typedef __attribute__((ext_vector_type(4))) float  f32x4;
typedef __attribute__((ext_vector_type(8))) unsigned short ushort8;

__device__ __forceinline__ unsigned short f2bf(float x) {
    __hip_bfloat16 h = __float2bfloat16(x);
    return *reinterpret_cast<unsigned short*>(&h);
}
__device__ __forceinline__ float bf2f(unsigned short u) {
    unsigned int v = ((unsigned int)u) << 16;
    return *reinterpret_cast<float*>(&v);
}

__device__ __forceinline__ void gload_lds16(const void* g, void* l) {
    __builtin_amdgcn_global_load_lds(
        (const __attribute__((address_space(1))) void*)g,
        (__attribute__((address_space(3))) void*)l,
        16, 0, 0);
}

// ---------------------------------------------------------------------------
// Fused weight prep: transpose [K=256][N] fp32 -> [N][K=256] bf16 for
// W_v (z=0), [W_off|W_aw] concat (z=1), W_out (z=2). Block (0,0,1) also
// writes bcat = [b_off|b_aw]. Grid (4,4,3), 256 threads.
// ---------------------------------------------------------------------------
__global__ __launch_bounds__(256) void prep_kernel(
    const float* __restrict__ W_v,  const float* __restrict__ W_off,
    const float* __restrict__ W_aw, const float* __restrict__ W_out,
    const float* __restrict__ b_off, const float* __restrict__ b_aw,
    unsigned short* __restrict__ Wv_t, unsigned short* __restrict__ Wcat_t,
    unsigned short* __restrict__ Wout_t, float* __restrict__ bcat)
{
    __shared__ float t[64][65];
    const int z   = blockIdx.z;
    const int k0  = blockIdx.y * 64;
    const int n0  = blockIdx.x * 64;
    const int tid = threadIdx.x;

    const float* src; int srcN; int cs; unsigned short* dst;
    if (z == 0)      { src = W_v;   srcN = 256; cs = n0;       dst = Wv_t;  }
    else if (z == 2) { src = W_out; srcN = 256; cs = n0;       dst = Wout_t;}
    else if (n0 < 128){ src = W_off; srcN = 128; cs = n0;      dst = Wcat_t;}
    else             { src = W_aw;  srcN = 128; cs = n0 - 128; dst = Wcat_t;}

    #pragma unroll
    for (int i = 0; i < 16; ++i) {
        int idx = tid + i * 256;
        int kk = idx >> 6, nn = idx & 63;
        t[kk][nn] = src[(size_t)(k0 + kk) * srcN + cs + nn];
    }
    __syncthreads();
    #pragma unroll
    for (int i = 0; i < 16; ++i) {
        int idx = tid + i * 256;
        int nn = idx >> 6, kk = idx & 63;
        dst[(size_t)(n0 + nn) * 256 + k0 + kk] = f2bf(t[kk][nn]);
    }
    if (z == 1 && blockIdx.x == 0 && blockIdx.y == 0) {
        bcat[tid] = (tid < 128) ? b_off[tid] : b_aw[tid - 128];
    }
}

// ---------------------------------------------------------------------------
// Pipelined value-GEMM + P-GEMM. 64x128 tiles, grid 1472, 256 thr (4 waves).
// job < 960 : value tile -> value3 bf16 [n][m][s][32]
// job >= 960: P tile     -> P fp32 [nq][256]
// A fp32 row-major, converted in-register while staging (frag-order LDS).
// B bf16 N-major via global_load_lds. Double-buffered LDS, ONE barrier per
// K-step; next-step loads issued after the barrier overlap current compute.
// Wave w owns rows w*16..w*16+15 x all 128 cols (8 MFMA / K-step).
// ---------------------------------------------------------------------------
__global__ __launch_bounds__(256) void gemm_vp_kernel(
    const float* __restrict__ inflat, const float* __restrict__ query,
    const unsigned short* __restrict__ Wv_t, const unsigned short* __restrict__ Wcat_t,
    const float* __restrict__ b_v, const float* __restrict__ bcat,
    unsigned short* __restrict__ value3, float* __restrict__ P)
{
    __shared__ alignas(16) unsigned short Abuf[2][4][64][8];   // 2 x 4 KiB
    __shared__ alignas(16) unsigned short Bbuf[2][8][64][8];   // 2 x 8 KiB

    const int job = blockIdx.x;
    const bool is_val = (job < 960);
    const int jj   = is_val ? job : (job - 960);
    const int row0 = (jj >> 1) * 64;
    const int col0 = (jj & 1) * 128;
    const float* A = is_val ? inflat : query;
    const unsigned short* Bt = is_val ? Wv_t : Wcat_t;
    const float* bias = is_val ? b_v : bcat;

    const int tid  = threadIdx.x;
    const int lane = tid & 63;
    const int w    = tid >> 6;
    const int lr   = lane & 15;
    const int lk   = (lane >> 4) * 8;

    // A staging map: thread -> (row ar, k-offset ak), packed to frag order
    const int ar = tid >> 2;            // 0..63
    const int ak = (tid & 3) * 8;       // 0,8,16,24
    const int afrag = ar >> 4;
    const int alane = ((ak >> 3) << 4) | (ar & 15);
    const float* Arow = A + (size_t)(row0 + ar) * 256 + ak;
    const unsigned short* Bcol = Bt + (size_t)(col0 + lr) * 256 + lk;

    f32x4 acc[8] = {};

    // prologue: k-step 0
    float4 pa0 = *(const float4*)(Arow);
    float4 pa1 = *(const float4*)(Arow + 4);
    #pragma unroll
    for (int c = 0; c < 2; ++c) {
        const int in = w * 2 + c;
        gload_lds16(Bcol + (size_t)in * 16 * 256, &Bbuf[0][in][0][0]);
    }

    for (int kt = 0; kt < 8; ++kt) {
        const int cur = kt & 1;
        // pack A(kt) into frag-order LDS
        short8 pk;
        pk[0] = (short)f2bf(pa0.x); pk[1] = (short)f2bf(pa0.y);
        pk[2] = (short)f2bf(pa0.z); pk[3] = (short)f2bf(pa0.w);
        pk[4] = (short)f2bf(pa1.x); pk[5] = (short)f2bf(pa1.y);
        pk[6] = (short)f2bf(pa1.z); pk[7] = (short)f2bf(pa1.w);
        *(short8*)&Abuf[cur][afrag][alane][0] = pk;
        __syncthreads();   // drains DMA(kt) + A writes; all bufs[cur] ready

        if (kt < 7) {      // issue next-step loads AFTER barrier -> overlap
            const int k1 = (kt + 1) * 32;
            pa0 = *(const float4*)(Arow + k1);
            pa1 = *(const float4*)(Arow + k1 + 4);
            #pragma unroll
            for (int c = 0; c < 2; ++c) {
                const int in = w * 2 + c;
                gload_lds16(Bcol + (size_t)in * 16 * 256 + k1, &Bbuf[1 - cur][in][0][0]);
            }
        }

        const short8 af = *(const short8*)&Abuf[cur][w][lane][0];
        #pragma unroll
        for (int j = 0; j < 8; ++j) {
            const short8 bf = *(const short8*)&Bbuf[cur][j][lane][0];
            acc[j] = __builtin_amdgcn_mfma_f32_16x16x32_bf16(af, bf, acc[j], 0, 0, 0);
        }
        // no second barrier: next step writes the other buffer
    }

    const int prow = (lane >> 4) * 4;
    const int pcol = lane & 15;
    const int rbase = row0 + w * 16 + prow;
    if (is_val) {
        const int n  = row0 / S_LEN;
        const int s0 = row0 - n * S_LEN + w * 16 + prow;
        #pragma unroll
        for (int j = 0; j < 8; ++j) {
            const int col = col0 + j * 16 + pcol;
            const float bs = bias[col];
            const int m = col >> 5, d = col & 31;
            unsigned short* dst = value3 + ((size_t)(n * 8 + m) * S_LEN + s0) * 32 + d;
            #pragma unroll
            for (int r = 0; r < 4; ++r)
                dst[(size_t)r * 32] = f2bf(acc[j][r] + bs);
        }
    } else {
        #pragma unroll
        for (int j = 0; j < 8; ++j) {
            const int col = col0 + j * 16 + pcol;
            const float bs = bias[col];
            #pragma unroll
            for (int r = 0; r < 4; ++r)
                P[(size_t)(rbase + r) * 256 + col] = acc[j][r] + bs;
        }
    }
}

// ---------------------------------------------------------------------------
// Sampling + softmax. 2048 blocks, 256 thr, QB=8 queries/block.
// blockIdx&7 -> (n, q-half): batch n's 3.93 MB value slice stays resident in
// the two XCDs serving it. Two barriers total; softmax computed redundantly
// in-register by each gather lane group (no extra phase / normalization pass).
// ---------------------------------------------------------------------------
__global__ __launch_bounds__(256) void sample_kernel(
    const float* __restrict__ P, const float* __restrict__ refp,
    const int* __restrict__ shapes, const int* __restrict__ lstart,
    const unsigned short* __restrict__ value3,
    unsigned short* __restrict__ tout)
{
    __shared__ int   sG0[QB][130];
    __shared__ float sW [QB][130];
    __shared__ float sA [QB][130];
    __shared__ int   glim[4];

    const int b    = blockIdx.x;       // 0..2047
    const int xcd  = b & 7;
    const int n    = xcd >> 1;
    const int half = xcd & 1;
    const int slot = b >> 3;           // 0..255
    const int q0   = (slot * 2 + half) * QB;
    const int nq0  = n * LQ + q0;
    const int tid  = threadIdx.x;

    if (tid < 4) glim[tid] = lstart[tid] + shapes[tid] - 1;

    // phase 1: 8 queries x 128 points
    #pragma unroll
    for (int it = 0; it < 4; ++it) {
        const int idx = tid + it * 256;   // 0..1023
        const int q   = idx >> 7;
        const int j   = idx & 127;        // m*16 + l*4 + p
        const int l   = (j >> 2) & 3;
        const int nq  = nq0 + q;
        const float off   = __builtin_nontemporal_load(P + (size_t)nq * 256 + j);
        const float logit = __builtin_nontemporal_load(P + (size_t)nq * 256 + 128 + j);
        const float ref   = __builtin_nontemporal_load(refp + (size_t)nq * N_LEVELS + l);
        const int   sh    = shapes[l];
        const float Tf    = (float)sh;
        float x = ref * Tf + off - 0.5f;
        x = fminf(fmaxf(x, 0.0f), Tf - 1.0f);
        const float x0 = floorf(x);
        sG0[q][j] = (int)x0 + lstart[l];
        sW [q][j] = x - x0;
        sA [q][j] = logit;
    }
    __syncthreads();

    // phase 2: gather + in-register softmax + interpolate
    const int q  = tid >> 5;          // 0..7
    const int r  = tid & 31;
    const int m  = r >> 2;            // head
    const int ql = r & 3;             // 8-dim group
    const unsigned short* vb =
        value3 + (size_t)(n * 8 + m) * S_LEN * 32 + ql * 8;

    float e[16];
    float mx = -1e30f;
    #pragma unroll
    for (int i = 0; i < 16; ++i) { e[i] = sA[q][m * 16 + i]; mx = fmaxf(mx, e[i]); }
    float s = 0.f;
    #pragma unroll
    for (int i = 0; i < 16; ++i) { e[i] = __expf(e[i] - mx); s += e[i]; }
    const float rs = 1.0f / s;

    float acc[8] = {};
    #pragma unroll
    for (int i = 0; i < 16; ++i) {
        const int j = m * 16 + i;
        const float a  = e[i] * rs;
        const float ww = sW[q][j];
        const int g0 = sG0[q][j];
        const int g1 = min(g0 + 1, glim[i >> 2]);
        const ushort8 u0 = *(const ushort8*)(vb + (size_t)g0 * 32);
        const ushort8 u1 = *(const ushort8*)(vb + (size_t)g1 * 32);
        #pragma unroll
        for (int d = 0; d < 8; ++d) {
            const float v0 = bf2f(u0[d]);
            const float v1 = bf2f(u1[d]);
            acc[d] += a * (v0 + ww * (v1 - v0));
        }
    }
    ushort8 o;
    #pragma unroll
    for (int d = 0; d < 8; ++d) o[d] = f2bf(acc[d]);
    __builtin_nontemporal_store(o,
        (ushort8*)(tout + (size_t)(nq0 + q) * 256 + m * 32 + ql * 8));
}

// ---------------------------------------------------------------------------
// Pipelined out-proj GEMM: C[16384,256] = tbuf @ Wout_t^T + b_out (fp32 out).
// 64x128 tiles, grid 512, same 1-barrier double-buffered structure; both A
// and B staged via global_load_lds (A bf16 row-major, frag order).
// ---------------------------------------------------------------------------
__global__ __launch_bounds__(256) void gemm_out_kernel(
    const unsigned short* __restrict__ A,
    const unsigned short* __restrict__ Bt,
    const float* __restrict__ bias,
    float* __restrict__ Cout)
{
    __shared__ alignas(16) unsigned short Abuf[2][4][64][8];
    __shared__ alignas(16) unsigned short Bbuf[2][8][64][8];

    const int jj   = blockIdx.x;
    const int row0 = (jj >> 1) * 64;
    const int col0 = (jj & 1) * 128;

    const int tid  = threadIdx.x;
    const int lane = tid & 63;
    const int w    = tid >> 6;
    const int lr   = lane & 15;
    const int lk   = (lane >> 4) * 8;

    const unsigned short* Arow = A + (size_t)(row0 + w * 16 + lr) * 256 + lk;
    const unsigned short* Bcol = Bt + (size_t)(col0 + lr) * 256 + lk;

    f32x4 acc[8] = {};

    // prologue
    gload_lds16(Arow, &Abuf[0][w][0][0]);
    #pragma unroll
    for (int c = 0; c < 2; ++c) {
        const int in = w * 2 + c;
        gload_lds16(Bcol + (size_t)in * 16 * 256, &Bbuf[0][in][0][0]);
    }

    for (int kt = 0; kt < 8; ++kt) {
        const int cur = kt & 1;
        __syncthreads();

        if (kt < 7) {
            const int k1 = (kt + 1) * 32;
            gload_lds16(Arow + k1, &Abuf[1 - cur][w][0][0]);
            #pragma unroll
            for (int c = 0; c < 2; ++c) {
                const int in = w * 2 + c;
                gload_lds16(Bcol + (size_t)in * 16 * 256 + k1, &Bbuf[1 - cur][in][0][0]);
            }
        }

        const short8 af = *(const short8*)&Abuf[cur][w][lane][0];
        #pragma unroll
        for (int j = 0; j < 8; ++j) {
            const short8 bf = *(const short8*)&Bbuf[cur][j][lane][0];
            acc[j] = __builtin_amdgcn_mfma_f32_16x16x32_bf16(af, bf, acc[j], 0, 0, 0);
        }
    }

    const int prow = (lane >> 4) * 4;
    const int pcol = lane & 15;
    const int rbase = row0 + w * 16 + prow;
    #pragma unroll
    for (int j = 0; j < 8; ++j) {
        const int col = col0 + j * 16 + pcol;
        const float bs = bias[col];
        #pragma unroll
        for (int r = 0; r < 4; ++r)
            Cout[(size_t)(rbase + r) * 256 + col] = acc[j][r] + bs;
    }
}

// ---------------------------------------------------------------------------
extern "C" void kernel_launch(void* const* d_in, const int* in_sizes, int n_in,
                              void* d_out, int out_size, void* d_ws, size_t ws_size,
                              hipStream_t stream)
{
    const float* query  = (const float*)d_in[0];
    const float* refp   = (const float*)d_in[1];
    const float* inflat = (const float*)d_in[2];
    const int*   shapes = (const int*)d_in[3];
    const int*   lstart = (const int*)d_in[4];
    const float* W_off  = (const float*)d_in[5];
    const float* b_off  = (const float*)d_in[6];
    const float* W_aw   = (const float*)d_in[7];
    const float* b_aw   = (const float*)d_in[8];
    const float* W_v    = (const float*)d_in[9];
    const float* b_v    = (const float*)d_in[10];
    const float* W_out  = (const float*)d_in[11];
    const float* b_out  = (const float*)d_in[12];

    const int M_val = NBATCH * S_LEN;    // 30720
    const int M_q   = NBATCH * LQ;       // 16384

    // ---- workspace layout ----
    char* p = (char*)d_ws;
    unsigned short* value3 = (unsigned short*)p; p += (size_t)M_val * D_MODEL * 2; // 15.7 MB
    float*          P      = (float*)p;          p += (size_t)M_q * 256 * 4;       // 16.8 MB
    unsigned short* tbuf   = (unsigned short*)p; p += (size_t)M_q * D_MODEL * 2;   // 8.4 MB
    unsigned short* Wv_t   = (unsigned short*)p; p += 256 * 256 * 2;
    unsigned short* Wcat_t = (unsigned short*)p; p += 256 * 256 * 2;
    unsigned short* Wout_t = (unsigned short*)p; p += 256 * 256 * 2;
    float*          bcat   = (float*)p;          p += 256 * 4;

    // 1. weight prep
    prep_kernel<<<dim3(4, 4, 3), 256, 0, stream>>>(
        W_v, W_off, W_aw, W_out, b_off, b_aw, Wv_t, Wcat_t, Wout_t, bcat);
    // 2. value-GEMM (960 jobs) + P-GEMM (512 jobs), one pipelined dispatch
    gemm_vp_kernel<<<1472, 256, 0, stream>>>(
        inflat, query, Wv_t, Wcat_t, b_v, bcat, value3, P);
    // 3. sampling + softmax -> tbuf (bf16)
    sample_kernel<<<2048, 256, 0, stream>>>(
        P, refp, shapes, lstart, value3, tbuf);
    // 4. out = tbuf @ W_out + b_out (pipelined)
    gemm_out_kernel<<<512, 256, 0, stream>>>(
        tbuf, Wout_t, b_out, (float*)d_out);
}